// Round 1
// baseline (52.203 us; speedup 1.0000x reference)
//
#include <hip/hip_runtime.h>

#define HAD_D 4096
#define PER_THREAD 64   // floats per lane (HAD_D / 64 lanes)
#define NVEC 16         // float4s per lane

// One wave (64 lanes) performs the full 4096-point FWHT for one row.
// Element ownership: e = 256*k + 4*lane + m  (k = float4 index 0..15, m = 0..3)
//  -> each float4 load/store instruction is a fully-coalesced 1 KiB wave access.
// Stage map (12 butterfly stages, order irrelevant since they commute):
//   h = 1, 2      : within each float4 (register-local)
//   h = 4..128    : lane-bit stages, __shfl_xor strides 1,2,4,8,16,32
//   h = 256..2048 : register-index-k stages (register-local)
__global__ __launch_bounds__(256) void fwht4096_kernel(const float* __restrict__ x,
                                                       float* __restrict__ out,
                                                       int nrows) {
    const int wave = threadIdx.x >> 6;
    const int lane = threadIdx.x & 63;
    const int row  = blockIdx.x * 4 + wave;
    if (row >= nrows) return;

    const float4* __restrict__ x4 = (const float4*)(x + (size_t)row * HAD_D);
    float4* __restrict__ y4       = (float4*)(out + (size_t)row * HAD_D);

    float v[PER_THREAD];

    #pragma unroll
    for (int k = 0; k < NVEC; ++k) {
        float4 t = x4[k * 64 + lane];
        v[4*k+0] = t.x; v[4*k+1] = t.y; v[4*k+2] = t.z; v[4*k+3] = t.w;
    }

    // Stages h=1 and h=2: inside each float4.
    #pragma unroll
    for (int k = 0; k < NVEC; ++k) {
        float a = v[4*k+0], b = v[4*k+1], c = v[4*k+2], d = v[4*k+3];
        float a1 = a + b, b1 = a - b, c1 = c + d, d1 = c - d;
        v[4*k+0] = a1 + c1;
        v[4*k+1] = b1 + d1;
        v[4*k+2] = a1 - c1;
        v[4*k+3] = b1 - d1;
    }

    // Stages h=4..128: cross-lane butterflies (lane-xor strides 1..32).
    // Low lane (bit clear) computes a+b; high lane computes a-b = partner-own.
    #pragma unroll
    for (int s = 1; s <= 32; s <<= 1) {
        const bool upper = (lane & s) != 0;
        #pragma unroll
        for (int j = 0; j < PER_THREAD; ++j) {
            float partner = __shfl_xor(v[j], s, 64);
            v[j] = upper ? (partner - v[j]) : (v[j] + partner);
        }
    }

    // Stages h=256..2048: register-index (k) butterflies, strides 1,2,4,8.
    #pragma unroll
    for (int s = 1; s <= 8; s <<= 1) {
        #pragma unroll
        for (int k = 0; k < NVEC; ++k) {
            if ((k & s) == 0) {
                #pragma unroll
                for (int m = 0; m < 4; ++m) {
                    float a = v[4*k+m], b = v[4*(k+s)+m];
                    v[4*k+m]     = a + b;
                    v[4*(k+s)+m] = a - b;
                }
            }
        }
    }

    #pragma unroll
    for (int k = 0; k < NVEC; ++k) {
        float4 t;
        t.x = v[4*k+0]; t.y = v[4*k+1]; t.z = v[4*k+2]; t.w = v[4*k+3];
        y4[k * 64 + lane] = t;
    }
}

extern "C" void kernel_launch(void* const* d_in, const int* in_sizes, int n_in,
                              void* d_out, int out_size, void* d_ws, size_t ws_size,
                              hipStream_t stream) {
    const float* x = (const float*)d_in[0];
    float* out     = (float*)d_out;
    const int nrows = in_sizes[0] / HAD_D;      // 8192
    const int blocks = (nrows + 3) / 4;         // 4 rows (waves) per block
    hipLaunchKernelGGL(fwht4096_kernel, dim3(blocks), dim3(256), 0, stream,
                       x, out, nrows);
}

// Round 3
// 47.464 us; speedup vs baseline: 1.0998x; 1.0998x over previous
//
#include <hip/hip_runtime.h>

#define HAD_D 4096
#define PER_THREAD 64   // floats per lane (HAD_D / 64 lanes)
#define NVEC 16         // float4s per lane

typedef float floatx4 __attribute__((ext_vector_type(4)));  // clang-native, OK for nontemporal builtins

// One wave (64 lanes) performs the full 4096-point FWHT for one row.
// Element ownership: e = 256*k + 4*lane + m  (k = float4 index 0..15, m = 0..3)
//  -> each float4 load/store instruction is a fully-coalesced 1 KiB wave access.
// Stage map (12 butterfly stages, order irrelevant since they commute):
//   h = 1, 2      : within each float4 (register-local)
//   h = 4..128    : lane-bit stages, __shfl_xor strides 1,2,4,8,16,32
//   h = 256..2048 : register-index-k stages (register-local)
//
// Stores are NONTEMPORAL: output (128 MiB) streams to HBM without allocating
// in L2/L3, so the 128 MiB input stays resident in the 256 MiB Infinity Cache
// across graph replays -> reads served at L3 bandwidth, writes at HBM BW.
__global__ __launch_bounds__(256) void fwht4096_kernel(const float* __restrict__ x,
                                                       float* __restrict__ out,
                                                       int nrows) {
    const int wave = threadIdx.x >> 6;
    const int lane = threadIdx.x & 63;
    const int row  = blockIdx.x * 4 + wave;
    if (row >= nrows) return;

    const floatx4* __restrict__ x4 = (const floatx4*)(x + (size_t)row * HAD_D);
    floatx4* __restrict__ y4       = (floatx4*)(out + (size_t)row * HAD_D);

    float v[PER_THREAD];

    #pragma unroll
    for (int k = 0; k < NVEC; ++k) {
        floatx4 t = x4[k * 64 + lane];
        v[4*k+0] = t.x; v[4*k+1] = t.y; v[4*k+2] = t.z; v[4*k+3] = t.w;
    }

    // Stages h=1 and h=2: inside each float4.
    #pragma unroll
    for (int k = 0; k < NVEC; ++k) {
        float a = v[4*k+0], b = v[4*k+1], c = v[4*k+2], d = v[4*k+3];
        float a1 = a + b, b1 = a - b, c1 = c + d, d1 = c - d;
        v[4*k+0] = a1 + c1;
        v[4*k+1] = b1 + d1;
        v[4*k+2] = a1 - c1;
        v[4*k+3] = b1 - d1;
    }

    // Stages h=4..128: cross-lane butterflies (lane-xor strides 1..32).
    // Low lane (bit clear) computes a+b; high lane computes a-b = partner-own.
    #pragma unroll
    for (int s = 1; s <= 32; s <<= 1) {
        const bool upper = (lane & s) != 0;
        #pragma unroll
        for (int j = 0; j < PER_THREAD; ++j) {
            float partner = __shfl_xor(v[j], s, 64);
            v[j] = upper ? (partner - v[j]) : (v[j] + partner);
        }
    }

    // Stages h=256..2048: register-index (k) butterflies, strides 1,2,4,8.
    #pragma unroll
    for (int s = 1; s <= 8; s <<= 1) {
        #pragma unroll
        for (int k = 0; k < NVEC; ++k) {
            if ((k & s) == 0) {
                #pragma unroll
                for (int m = 0; m < 4; ++m) {
                    float a = v[4*k+m], b = v[4*(k+s)+m];
                    v[4*k+m]     = a + b;
                    v[4*(k+s)+m] = a - b;
                }
            }
        }
    }

    #pragma unroll
    for (int k = 0; k < NVEC; ++k) {
        floatx4 t;
        t.x = v[4*k+0]; t.y = v[4*k+1]; t.z = v[4*k+2]; t.w = v[4*k+3];
        __builtin_nontemporal_store(t, y4 + k * 64 + lane);
    }
}

extern "C" void kernel_launch(void* const* d_in, const int* in_sizes, int n_in,
                              void* d_out, int out_size, void* d_ws, size_t ws_size,
                              hipStream_t stream) {
    const float* x = (const float*)d_in[0];
    float* out     = (float*)d_out;
    const int nrows = in_sizes[0] / HAD_D;      // 8192
    const int blocks = (nrows + 3) / 4;         // 4 rows (waves) per block
    hipLaunchKernelGGL(fwht4096_kernel, dim3(blocks), dim3(256), 0, stream,
                       x, out, nrows);
}